// Round 1
// baseline (5998.395 us; speedup 1.0000x reference)
//
#include <hip/hip_runtime.h>

#define B_    32
#define N_    1176
#define C_    768
#define H_    12
#define HD_   64
#define NMT_  392
#define NS_   784
#define AG_   49
#define SCALE_ 0.125f

// ------------------------------------------------------------------
// GEMM: out = A @ Bm^T + bias.  A:(37632,768) row-major, Bm:(Ncols,768).
// OUT_MODE 0: Ncols=2304, scatter into q/k/v buffers, layout (B,H,N,64).
// OUT_MODE 1: Ncols=768, plain row-major out.
// ------------------------------------------------------------------
template <int OUT_MODE>
__global__ __launch_bounds__(256) void gemm_abT(
    const float* __restrict__ A, const float* __restrict__ Bm,
    const float* __restrict__ bias, float* __restrict__ out,
    float* __restrict__ qb, float* __restrict__ kb, float* __restrict__ vb) {
  __shared__ float As[16][68];
  __shared__ float Bs[16][68];
  const int tid = threadIdx.x;
  const int m0 = blockIdx.x * 64;
  const int c0 = blockIdx.y * 64;
  const int tx = tid & 15, ty = tid >> 4;
  const int lm = tid >> 2;         // 0..63 tile row
  const int lk4 = (tid & 3) << 2;  // k offset within 16
  float acc[4][4] = {};

  for (int k0 = 0; k0 < 768; k0 += 16) {
    float4 av = *(const float4*)&A[(m0 + lm) * 768 + k0 + lk4];
    float4 bv = *(const float4*)&Bm[(c0 + lm) * 768 + k0 + lk4];
    As[lk4 + 0][lm] = av.x; As[lk4 + 1][lm] = av.y;
    As[lk4 + 2][lm] = av.z; As[lk4 + 3][lm] = av.w;
    Bs[lk4 + 0][lm] = bv.x; Bs[lk4 + 1][lm] = bv.y;
    Bs[lk4 + 2][lm] = bv.z; Bs[lk4 + 3][lm] = bv.w;
    __syncthreads();
#pragma unroll
    for (int kk = 0; kk < 16; ++kk) {
      const float4 a = *(const float4*)&As[kk][ty * 4];
      const float4 b = *(const float4*)&Bs[kk][tx * 4];
      const float ar[4] = {a.x, a.y, a.z, a.w};
      const float br[4] = {b.x, b.y, b.z, b.w};
#pragma unroll
      for (int i = 0; i < 4; ++i)
#pragma unroll
        for (int j = 0; j < 4; ++j) acc[i][j] = fmaf(ar[i], br[j], acc[i][j]);
    }
    __syncthreads();
  }

  if (OUT_MODE == 0) {
    const int cb = blockIdx.y;                // 0..35 = (t,h) block
    const int t = cb / 12, h = cb % 12;
    float* dst = (t == 0) ? qb : ((t == 1) ? kb : vb);
    const int d = tx * 4;
#pragma unroll
    for (int i = 0; i < 4; ++i) {
      const int m = m0 + ty * 4 + i;
      const int b = m / N_, n = m % N_;
      float4 o;
      o.x = acc[i][0] + bias[cb * 64 + d + 0];
      o.y = acc[i][1] + bias[cb * 64 + d + 1];
      o.z = acc[i][2] + bias[cb * 64 + d + 2];
      o.w = acc[i][3] + bias[cb * 64 + d + 3];
      *(float4*)&dst[((b * H_ + h) * N_ + n) * HD_ + d] = o;
    }
  } else {
    const int c = blockIdx.y * 64 + tx * 4;
#pragma unroll
    for (int i = 0; i < 4; ++i) {
      const int m = m0 + ty * 4 + i;
      float4 o;
      o.x = acc[i][0] + bias[c + 0];
      o.y = acc[i][1] + bias[c + 1];
      o.z = acc[i][2] + bias[c + 2];
      o.w = acc[i][3] + bias[c + 3];
      *(float4*)&out[m * C_ + c] = o;
    }
  }
}

// ------------------------------------------------------------------
// Agent pooling — replicates the reference's scrambled reshape exactly.
// agent[b,h2,a,d] = 1/16 * sum_{i,j} q[b, g/784, NMT_+g%784, d],
//   g = (ap*4+i)*336 + (aq*4+j)*12 + h2,  a = ap*7+aq.
// ------------------------------------------------------------------
__global__ __launch_bounds__(256) void agent_pool(const float* __restrict__ q,
                                                  float* __restrict__ agent) {
  const int wid = threadIdx.x >> 6;
  const int lane = threadIdx.x & 63;
  const int row = blockIdx.x * 4 + wid;  // 0..18815 = (b*12+h2)*49+a
  const int rem = row % (H_ * AG_);
  const int b = row / (H_ * AG_);
  const int h2 = rem / AG_;
  const int a = rem % AG_;
  const int ap = a / 7, aq = a % 7;
  float s = 0.f;
#pragma unroll
  for (int i = 0; i < 4; ++i)
#pragma unroll
    for (int j = 0; j < 4; ++j) {
      const int g = (ap * 4 + i) * 336 + (aq * 4 + j) * 12 + h2;
      const int h = g / 784, n = g % 784;
      s += q[((b * H_ + h) * N_ + NMT_ + n) * HD_ + lane];
    }
  agent[row * HD_ + lane] = s * 0.0625f;
}

// ------------------------------------------------------------------
// MT attention: per (b,h), 392 q rows x 392 keys, flash-style.
// Writes x_mt rows [0,392) of the concat buffer.
// ------------------------------------------------------------------
__global__ __launch_bounds__(256) void attn_mt(const float* __restrict__ q,
                                               const float* __restrict__ k,
                                               const float* __restrict__ v,
                                               float* __restrict__ xout) {
  const int bh = blockIdx.x;  // b*12+h
  const int qt = blockIdx.y;  // 0..6
  const int tid = threadIdx.x;
  __shared__ float Qs[56][68], Ks[56][68], Vs[56][68], Ss[56][57];
  __shared__ float mS[56], lS[56], aS[56];

  const float* qbase = q + (bh * N_ + qt * 56) * HD_;
  for (int it = tid; it < 56 * 16; it += 256) {
    const int r = it >> 4, c4 = (it & 15) << 2;
    *(float4*)&Qs[r][c4] = *(const float4*)&qbase[r * HD_ + c4];
  }
  if (tid < 56) { mS[tid] = -1e30f; lS[tid] = 0.f; }
  float oacc[14];
#pragma unroll
  for (int i = 0; i < 14; ++i) oacc[i] = 0.f;
  __syncthreads();

  for (int kt = 0; kt < 7; ++kt) {
    const float* kbase = k + (bh * N_ + kt * 56) * HD_;
    const float* vbase = v + (bh * N_ + kt * 56) * HD_;
    for (int it = tid; it < 56 * 16; it += 256) {
      const int r = it >> 4, c4 = (it & 15) << 2;
      *(float4*)&Ks[r][c4] = *(const float4*)&kbase[r * HD_ + c4];
      *(float4*)&Vs[r][c4] = *(const float4*)&vbase[r * HD_ + c4];
    }
    __syncthreads();
    for (int idx = tid; idx < 56 * 56; idx += 256) {
      const int qq = idx / 56, kk = idx % 56;
      float s = 0.f;
#pragma unroll
      for (int d4 = 0; d4 < 16; ++d4) {
        const float4 qa = *(const float4*)&Qs[qq][d4 * 4];
        const float4 ka = *(const float4*)&Ks[kk][d4 * 4];
        s += qa.x * ka.x + qa.y * ka.y + qa.z * ka.z + qa.w * ka.w;
      }
      Ss[qq][kk] = s * SCALE_;
    }
    __syncthreads();
    if (tid < 224) {
      const int r = tid >> 2, j = tid & 3;
      float mx = -1e30f;
      for (int kk = j; kk < 56; kk += 4) mx = fmaxf(mx, Ss[r][kk]);
      mx = fmaxf(mx, __shfl_xor(mx, 1));
      mx = fmaxf(mx, __shfl_xor(mx, 2));
      const float mold = mS[r];
      const float mnew = fmaxf(mold, mx);
      float sum = 0.f;
      for (int kk = j; kk < 56; kk += 4) {
        const float p = __expf(Ss[r][kk] - mnew);
        Ss[r][kk] = p;
        sum += p;
      }
      sum += __shfl_xor(sum, 1);
      sum += __shfl_xor(sum, 2);
      if (j == 0) {
        const float alpha = __expf(mold - mnew);
        aS[r] = alpha;
        lS[r] = lS[r] * alpha + sum;
        mS[r] = mnew;
      }
    }
    __syncthreads();
#pragma unroll
    for (int it = 0; it < 14; ++it) {
      const int idx = tid + it * 256;
      const int qq = idx >> 6, d = idx & 63;
      float o = oacc[it] * aS[qq];
      for (int kk = 0; kk < 56; ++kk) o = fmaf(Ss[qq][kk], Vs[kk][d], o);
      oacc[it] = o;
    }
    __syncthreads();
  }

  const int b = bh / H_, h = bh % H_;
#pragma unroll
  for (int it = 0; it < 14; ++it) {
    const int idx = tid + it * 256;
    const int qq = idx >> 6, d = idx & 63;
    const int m = b * N_ + qt * 56 + qq;
    xout[m * C_ + h * HD_ + d] = oacc[it] / lS[qq];
  }
}

// ------------------------------------------------------------------
// Agent attention: per (b,h), 49 agents x all 1176 keys, flash-style.
// ------------------------------------------------------------------
__global__ __launch_bounds__(256) void attn_agent(
    const float* __restrict__ agent, const float* __restrict__ k,
    const float* __restrict__ v, float* __restrict__ agent_v) {
  const int bh = blockIdx.x;
  const int tid = threadIdx.x;
  __shared__ float Gs[49][68], Ks[56][68], Vs[56][68], Ss[49][57];
  __shared__ float mS[49], lS[49], aS[49];

  for (int it = tid; it < 49 * 16; it += 256) {
    const int r = it >> 4, c4 = (it & 15) << 2;
    *(float4*)&Gs[r][c4] = *(const float4*)&agent[(bh * AG_ + r) * HD_ + c4];
  }
  if (tid < 49) { mS[tid] = -1e30f; lS[tid] = 0.f; }
  float oacc[13];
#pragma unroll
  for (int i = 0; i < 13; ++i) oacc[i] = 0.f;
  __syncthreads();

  for (int kt = 0; kt < 21; ++kt) {
    const float* kbase = k + (bh * N_ + kt * 56) * HD_;
    const float* vbase = v + (bh * N_ + kt * 56) * HD_;
    for (int it = tid; it < 56 * 16; it += 256) {
      const int r = it >> 4, c4 = (it & 15) << 2;
      *(float4*)&Ks[r][c4] = *(const float4*)&kbase[r * HD_ + c4];
      *(float4*)&Vs[r][c4] = *(const float4*)&vbase[r * HD_ + c4];
    }
    __syncthreads();
    for (int idx = tid; idx < 49 * 56; idx += 256) {
      const int qq = idx / 56, kk = idx % 56;
      float s = 0.f;
#pragma unroll
      for (int d4 = 0; d4 < 16; ++d4) {
        const float4 qa = *(const float4*)&Gs[qq][d4 * 4];
        const float4 ka = *(const float4*)&Ks[kk][d4 * 4];
        s += qa.x * ka.x + qa.y * ka.y + qa.z * ka.z + qa.w * ka.w;
      }
      Ss[qq][kk] = s * SCALE_;
    }
    __syncthreads();
    if (tid < 196) {
      const int r = tid >> 2, j = tid & 3;
      float mx = -1e30f;
      for (int kk = j; kk < 56; kk += 4) mx = fmaxf(mx, Ss[r][kk]);
      mx = fmaxf(mx, __shfl_xor(mx, 1));
      mx = fmaxf(mx, __shfl_xor(mx, 2));
      const float mold = mS[r];
      const float mnew = fmaxf(mold, mx);
      float sum = 0.f;
      for (int kk = j; kk < 56; kk += 4) {
        const float p = __expf(Ss[r][kk] - mnew);
        Ss[r][kk] = p;
        sum += p;
      }
      sum += __shfl_xor(sum, 1);
      sum += __shfl_xor(sum, 2);
      if (j == 0) {
        const float alpha = __expf(mold - mnew);
        aS[r] = alpha;
        lS[r] = lS[r] * alpha + sum;
        mS[r] = mnew;
      }
    }
    __syncthreads();
#pragma unroll
    for (int it = 0; it < 13; ++it) {
      const int idx = tid + it * 256;
      if (idx < AG_ * HD_) {
        const int qq = idx >> 6, d = idx & 63;
        float o = oacc[it] * aS[qq];
        for (int kk = 0; kk < 56; ++kk) o = fmaf(Ss[qq][kk], Vs[kk][d], o);
        oacc[it] = o;
      }
    }
    __syncthreads();
  }
#pragma unroll
  for (int it = 0; it < 13; ++it) {
    const int idx = tid + it * 256;
    if (idx < AG_ * HD_) {
      const int qq = idx >> 6, d = idx & 63;
      agent_v[(bh * AG_ + qq) * HD_ + d] = oacc[it] / lS[qq];
    }
  }
}

// ------------------------------------------------------------------
// q_s attention over 49 agents + PV with agent_v.  Writes x_s rows
// [392,1176) of the concat buffer.
// ------------------------------------------------------------------
__global__ __launch_bounds__(256) void attn_qs(const float* __restrict__ q,
                                               const float* __restrict__ agent,
                                               const float* __restrict__ agent_v,
                                               float* __restrict__ xout) {
  const int bh = blockIdx.x;
  const int qt = blockIdx.y;  // 0..13
  const int tid = threadIdx.x;
  __shared__ float Qs[56][68], Gs[49][68], Vs[49][68], Ss[56][53];

  const float* qbase = q + (bh * N_ + NMT_ + qt * 56) * HD_;
  for (int it = tid; it < 56 * 16; it += 256) {
    const int r = it >> 4, c4 = (it & 15) << 2;
    *(float4*)&Qs[r][c4] = *(const float4*)&qbase[r * HD_ + c4];
  }
  for (int it = tid; it < 49 * 16; it += 256) {
    const int r = it >> 4, c4 = (it & 15) << 2;
    *(float4*)&Gs[r][c4] = *(const float4*)&agent[(bh * AG_ + r) * HD_ + c4];
    *(float4*)&Vs[r][c4] = *(const float4*)&agent_v[(bh * AG_ + r) * HD_ + c4];
  }
  __syncthreads();
  for (int idx = tid; idx < 56 * AG_; idx += 256) {
    const int qq = idx / AG_, a = idx % AG_;
    float s = 0.f;
#pragma unroll
    for (int d4 = 0; d4 < 16; ++d4) {
      const float4 qa = *(const float4*)&Qs[qq][d4 * 4];
      const float4 ga = *(const float4*)&Gs[a][d4 * 4];
      s += qa.x * ga.x + qa.y * ga.y + qa.z * ga.z + qa.w * ga.w;
    }
    Ss[qq][a] = s * SCALE_;
  }
  __syncthreads();
  if (tid < 224) {
    const int r = tid >> 2, j = tid & 3;
    float mx = -1e30f;
    for (int a = j; a < AG_; a += 4) mx = fmaxf(mx, Ss[r][a]);
    mx = fmaxf(mx, __shfl_xor(mx, 1));
    mx = fmaxf(mx, __shfl_xor(mx, 2));
    float sum = 0.f;
    for (int a = j; a < AG_; a += 4) sum += __expf(Ss[r][a] - mx);
    sum += __shfl_xor(sum, 1);
    sum += __shfl_xor(sum, 2);
    const float inv = 1.f / sum;
    for (int a = j; a < AG_; a += 4) Ss[r][a] = __expf(Ss[r][a] - mx) * inv;
  }
  __syncthreads();
  const int b = bh / H_, h = bh % H_;
#pragma unroll
  for (int it = 0; it < 14; ++it) {
    const int idx = tid + it * 256;
    const int qq = idx >> 6, d = idx & 63;
    float o = 0.f;
    for (int a = 0; a < AG_; ++a) o = fmaf(Ss[qq][a], Vs[a][d], o);
    const int m = b * N_ + NMT_ + qt * 56 + qq;
    xout[m * C_ + h * HD_ + d] = o;
  }
}

// ------------------------------------------------------------------
// Fallback in-place projection (reads+writes d_out) for small ws.
// Block stages its 32 rows fully into LDS first -> in-place safe.
// ------------------------------------------------------------------
__global__ __launch_bounds__(256) void proj_inplace(
    const float* __restrict__ w, const float* __restrict__ bias,
    float* __restrict__ xio) {
  __shared__ float Xs[32][772];
  __shared__ float Ws[16][68];
  const int tid = threadIdx.x;
  const int r0 = blockIdx.x * 32;
  for (int it = tid; it < 32 * 192; it += 256) {
    const int r = it / 192, c4 = (it % 192) * 4;
    *(float4*)&Xs[r][c4] = *(const float4*)&xio[(r0 + r) * C_ + c4];
  }
  __syncthreads();
  const int tx = tid & 15, ty = tid >> 4;
  for (int ct = 0; ct < 12; ++ct) {
    const int c0 = ct * 64;
    float acc[2][4] = {};
    for (int kt = 0; kt < 48; ++kt) {
      {
        const int cc = tid >> 2, k4 = (tid & 3) << 2;
        const float4 wv = *(const float4*)&w[(c0 + cc) * C_ + kt * 16 + k4];
        Ws[k4 + 0][cc] = wv.x; Ws[k4 + 1][cc] = wv.y;
        Ws[k4 + 2][cc] = wv.z; Ws[k4 + 3][cc] = wv.w;
      }
      __syncthreads();
#pragma unroll
      for (int kk = 0; kk < 16; ++kk) {
        const int kg = kt * 16 + kk;
        const float a0 = Xs[ty * 2 + 0][kg];
        const float a1 = Xs[ty * 2 + 1][kg];
        const float4 wv = *(const float4*)&Ws[kk][tx * 4];
        acc[0][0] = fmaf(a0, wv.x, acc[0][0]);
        acc[0][1] = fmaf(a0, wv.y, acc[0][1]);
        acc[0][2] = fmaf(a0, wv.z, acc[0][2]);
        acc[0][3] = fmaf(a0, wv.w, acc[0][3]);
        acc[1][0] = fmaf(a1, wv.x, acc[1][0]);
        acc[1][1] = fmaf(a1, wv.y, acc[1][1]);
        acc[1][2] = fmaf(a1, wv.z, acc[1][2]);
        acc[1][3] = fmaf(a1, wv.w, acc[1][3]);
      }
      __syncthreads();
    }
#pragma unroll
    for (int i = 0; i < 2; ++i) {
      const int r = r0 + ty * 2 + i;
      float4 o;
      o.x = acc[i][0] + bias[c0 + tx * 4 + 0];
      o.y = acc[i][1] + bias[c0 + tx * 4 + 1];
      o.z = acc[i][2] + bias[c0 + tx * 4 + 2];
      o.w = acc[i][3] + bias[c0 + tx * 4 + 3];
      *(float4*)&xio[r * C_ + c0 + tx * 4] = o;
    }
  }
}

// ------------------------------------------------------------------
extern "C" void kernel_launch(void* const* d_in, const int* in_sizes, int n_in,
                              void* d_out, int out_size, void* d_ws,
                              size_t ws_size, hipStream_t stream) {
  const float* x = (const float*)d_in[0];
  const float* qkv_w = (const float*)d_in[1];
  const float* qkv_b = (const float*)d_in[2];
  const float* proj_w = (const float*)d_in[3];
  const float* proj_b = (const float*)d_in[4];
  float* out = (float*)d_out;
  float* ws = (float*)d_ws;

  const size_t BHND = (size_t)B_ * H_ * N_ * HD_;      // 28,901,376 floats
  const size_t AGSZ = (size_t)B_ * H_ * AG_ * HD_;     // 1,204,224 floats
  float* qb = ws;
  float* kb = ws + BHND;
  float* vb = ws + 2 * BHND;
  float* agent = ws + 3 * BHND;
  float* agentv = agent + AGSZ;
  float* concat = agentv + AGSZ;
  const size_t need_full = (4 * BHND + 2 * AGSZ) * sizeof(float);
  const bool full = ws_size >= need_full;
  float* xcat = full ? concat : out;

  gemm_abT<0><<<dim3(588, 36), 256, 0, stream>>>(x, qkv_w, qkv_b, nullptr, qb,
                                                 kb, vb);
  agent_pool<<<dim3(4704), 256, 0, stream>>>(qb, agent);
  attn_agent<<<dim3(384), 256, 0, stream>>>(agent, kb, vb, agentv);
  attn_mt<<<dim3(384, 7), 256, 0, stream>>>(qb, kb, vb, xcat);
  attn_qs<<<dim3(384, 14), 256, 0, stream>>>(qb, agent, agentv, xcat);
  if (full) {
    gemm_abT<1><<<dim3(588, 12), 256, 0, stream>>>(concat, proj_w, proj_b, out,
                                                   nullptr, nullptr, nullptr);
  } else {
    proj_inplace<<<dim3(1176), 256, 0, stream>>>(proj_w, proj_b, out);
  }
}

// Round 2
// 2353.114 us; speedup vs baseline: 2.5491x; 2.5491x over previous
//
#include <hip/hip_runtime.h>

typedef __attribute__((ext_vector_type(8))) short short8;
typedef __attribute__((ext_vector_type(4))) float f32x4;

#define B_    32
#define N_    1176
#define C_    768
#define H_    12
#define HD_   64
#define NMT_  392
#define AG_   49
#define SCALE_ 0.125f

__device__ __forceinline__ unsigned short f2bf(float f) {
  unsigned u = __float_as_uint(f);
  unsigned r = (u + 0x7fffu + ((u >> 16) & 1u)) >> 16;
  return (unsigned short)r;
}
__device__ __forceinline__ float bf2f(unsigned short s) {
  return __uint_as_float(((unsigned)s) << 16);
}

// ------------------------------------------------------------------
// Split-bf16 GEMM: out = A @ Bw^T + bias.  A:(M,768) fp32, Bw:(Ncols,768) fp32.
// A,B each split into hi/lo bf16; 3-term MFMA (AhBh + AhBl + AlBh) ~ fp32.
// 128x128 tile, BK=32, 4 waves (2x2 of 64x64), double-buffered LDS.
// EPI 0: Ncols=2304, scatter to q/k/v (chunk-local b,h,n,d). EPI 1: row-major out.
// ------------------------------------------------------------------
template <int EPI>
__global__ __launch_bounds__(256, 2) void gemm_split(
    const float* __restrict__ A, const float* __restrict__ Bw,
    const float* __restrict__ bias, float* __restrict__ out,
    float* __restrict__ qb, float* __restrict__ kb, float* __restrict__ vb,
    int Mchunk) {
  __shared__ short Ah[2][128 * 32], Al[2][128 * 32];
  __shared__ short Bh[2][128 * 32], Bl[2][128 * 32];
  const int tid = threadIdx.x;
  const int m0 = blockIdx.x * 128, c0 = blockIdx.y * 128;
  const int row = tid >> 1, cc = tid & 1;   // staging: row 0..127, 16-elem half
  const int lane = tid & 63, wv = tid >> 6;
  const int wr = wv >> 1, wc = wv & 1;      // 2x2 wave grid
  const int fr = lane & 15, ko = lane >> 4; // fragment row / k-octet

  f32x4 acc[4][4];
#pragma unroll
  for (int i = 0; i < 4; ++i)
#pragma unroll
    for (int j = 0; j < 4; ++j) acc[i][j] = (f32x4)0.f;

  float ar[16], br[16];

  auto LOAD = [&](int kt) {
    const int am = min(m0 + row, Mchunk - 1);
    const float* pa = &A[(size_t)am * 768 + kt * 32 + cc * 16];
    const float* pb = &Bw[(size_t)(c0 + row) * 768 + kt * 32 + cc * 16];
#pragma unroll
    for (int i = 0; i < 4; ++i) {
      *(float4*)&ar[i * 4] = *(const float4*)&pa[i * 4];
      *(float4*)&br[i * 4] = *(const float4*)&pb[i * 4];
    }
  };

  auto WRITE = [&](int b) {
    const int off = row * 32 + cc * 16;
    short8 h0, h1, l0, l1;
#pragma unroll
    for (int i = 0; i < 8; ++i) {
      unsigned short h = f2bf(ar[i]);
      h0[i] = (short)h; l0[i] = (short)f2bf(ar[i] - bf2f(h));
    }
#pragma unroll
    for (int i = 0; i < 8; ++i) {
      unsigned short h = f2bf(ar[8 + i]);
      h1[i] = (short)h; l1[i] = (short)f2bf(ar[8 + i] - bf2f(h));
    }
    *(short8*)&Ah[b][off] = h0; *(short8*)&Ah[b][off + 8] = h1;
    *(short8*)&Al[b][off] = l0; *(short8*)&Al[b][off + 8] = l1;
#pragma unroll
    for (int i = 0; i < 8; ++i) {
      unsigned short h = f2bf(br[i]);
      h0[i] = (short)h; l0[i] = (short)f2bf(br[i] - bf2f(h));
    }
#pragma unroll
    for (int i = 0; i < 8; ++i) {
      unsigned short h = f2bf(br[8 + i]);
      h1[i] = (short)h; l1[i] = (short)f2bf(br[8 + i] - bf2f(h));
    }
    *(short8*)&Bh[b][off] = h0; *(short8*)&Bh[b][off + 8] = h1;
    *(short8*)&Bl[b][off] = l0; *(short8*)&Bl[b][off + 8] = l1;
  };

  auto COMPUTE = [&](int b) {
    short8 a_h[4], a_l[4], b_h[4], b_l[4];
#pragma unroll
    for (int m = 0; m < 4; ++m) {
      const int off = (wr * 64 + m * 16 + fr) * 32 + ko * 8;
      a_h[m] = *(const short8*)&Ah[b][off];
      a_l[m] = *(const short8*)&Al[b][off];
    }
#pragma unroll
    for (int n = 0; n < 4; ++n) {
      const int off = (wc * 64 + n * 16 + fr) * 32 + ko * 8;
      b_h[n] = *(const short8*)&Bh[b][off];
      b_l[n] = *(const short8*)&Bl[b][off];
    }
#pragma unroll
    for (int m = 0; m < 4; ++m)
#pragma unroll
      for (int n = 0; n < 4; ++n) {
        acc[m][n] = __builtin_amdgcn_mfma_f32_16x16x32_bf16(a_h[m], b_h[n], acc[m][n], 0, 0, 0);
        acc[m][n] = __builtin_amdgcn_mfma_f32_16x16x32_bf16(a_h[m], b_l[n], acc[m][n], 0, 0, 0);
        acc[m][n] = __builtin_amdgcn_mfma_f32_16x16x32_bf16(a_l[m], b_h[n], acc[m][n], 0, 0, 0);
      }
  };

  LOAD(0); WRITE(0); __syncthreads();
  for (int kt = 0; kt < 24; ++kt) {
    if (kt < 23) LOAD(kt + 1);
    COMPUTE(kt & 1);
    if (kt < 23) WRITE((kt + 1) & 1);
    __syncthreads();
  }

  if (EPI == 0) {
    const int colbase = c0 + wc * 64;  // 64-aligned -> t,h uniform per wave
    const int t = colbase / 768;
    const int h = (colbase % 768) >> 6;
    float* dst = (t == 0) ? qb : (t == 1 ? kb : vb);
#pragma unroll
    for (int n = 0; n < 4; ++n) {
      const float bv = bias[colbase + n * 16 + fr];
      const int d = ((colbase + n * 16) & 63) + fr;
#pragma unroll
      for (int m = 0; m < 4; ++m)
#pragma unroll
        for (int r = 0; r < 4; ++r) {
          const int mg = m0 + wr * 64 + m * 16 + (lane >> 4) * 4 + r;
          if (mg < Mchunk) {
            const int bl = mg / N_, nt = mg - bl * N_;
            dst[(((size_t)bl * H_ + h) * N_ + nt) * HD_ + d] = acc[m][n][r] + bv;
          }
        }
    }
  } else {
#pragma unroll
    for (int n = 0; n < 4; ++n) {
      const int col = c0 + wc * 64 + n * 16 + fr;
      const float bv = bias[col];
#pragma unroll
      for (int m = 0; m < 4; ++m)
#pragma unroll
        for (int r = 0; r < 4; ++r) {
          const int mg = m0 + wr * 64 + m * 16 + (lane >> 4) * 4 + r;
          if (mg < Mchunk) out[(size_t)mg * 768 + col] = acc[m][n][r] + bv;
        }
    }
  }
}

// ------------------------------------------------------------------
// Agent pooling — replicates the reference's scrambled reshape exactly.
// ------------------------------------------------------------------
__global__ __launch_bounds__(256) void agent_pool(const float* __restrict__ q,
                                                  float* __restrict__ agent) {
  const int wid = threadIdx.x >> 6;
  const int lane = threadIdx.x & 63;
  const int row = blockIdx.x * 4 + wid;  // chunk-local (b*12+h2)*49+a
  const int rem = row % (H_ * AG_);
  const int b = row / (H_ * AG_);
  const int h2 = rem / AG_;
  const int a = rem % AG_;
  const int ap = a / 7, aq = a % 7;
  float s = 0.f;
#pragma unroll
  for (int i = 0; i < 4; ++i)
#pragma unroll
    for (int j = 0; j < 4; ++j) {
      const int g = (ap * 4 + i) * 336 + (aq * 4 + j) * 12 + h2;
      const int h = g / 784, n = g % 784;
      s += q[(((size_t)b * H_ + h) * N_ + NMT_ + n) * HD_ + lane];
    }
  agent[(size_t)row * HD_ + lane] = s * 0.0625f;
}

// ------------------------------------------------------------------
// MT attention (flash): per chunk-local (b,h), 392 q x 392 k. float4 PV.
// ------------------------------------------------------------------
__global__ __launch_bounds__(256) void attn_mt(const float* __restrict__ q,
                                               const float* __restrict__ k,
                                               const float* __restrict__ v,
                                               float* __restrict__ xout, int b0) {
  const int bh = blockIdx.x;
  const int qt = blockIdx.y;
  const int tid = threadIdx.x;
  __shared__ float Qs[56][68], Ks[56][68], Vs[56][68], Ss[56][57];
  __shared__ float mS[56], lS[56], aS[56];

  const float* qbase = q + ((size_t)bh * N_ + qt * 56) * HD_;
  for (int it = tid; it < 56 * 16; it += 256) {
    const int r = it >> 4, c4 = (it & 15) << 2;
    *(float4*)&Qs[r][c4] = *(const float4*)&qbase[r * HD_ + c4];
  }
  if (tid < 56) { mS[tid] = -1e30f; lS[tid] = 0.f; }
  const int d4 = tid & 15, qoff = tid >> 4;
  f32x4 o4[4];
#pragma unroll
  for (int p = 0; p < 4; ++p) o4[p] = (f32x4)0.f;
  __syncthreads();

  for (int kt = 0; kt < 7; ++kt) {
    const float* kbase = k + ((size_t)bh * N_ + kt * 56) * HD_;
    const float* vbase = v + ((size_t)bh * N_ + kt * 56) * HD_;
    for (int it = tid; it < 56 * 16; it += 256) {
      const int r = it >> 4, c4 = (it & 15) << 2;
      *(float4*)&Ks[r][c4] = *(const float4*)&kbase[r * HD_ + c4];
      *(float4*)&Vs[r][c4] = *(const float4*)&vbase[r * HD_ + c4];
    }
    __syncthreads();
    for (int idx = tid; idx < 56 * 56; idx += 256) {
      const int qq = idx / 56, kk = idx % 56;
      float s = 0.f;
#pragma unroll
      for (int dd = 0; dd < 16; ++dd) {
        const float4 qa = *(const float4*)&Qs[qq][dd * 4];
        const float4 ka = *(const float4*)&Ks[kk][dd * 4];
        s += qa.x * ka.x + qa.y * ka.y + qa.z * ka.z + qa.w * ka.w;
      }
      Ss[qq][kk] = s * SCALE_;
    }
    __syncthreads();
    if (tid < 224) {
      const int r = tid >> 2, j = tid & 3;
      float mx = -1e30f;
      for (int kk = j; kk < 56; kk += 4) mx = fmaxf(mx, Ss[r][kk]);
      mx = fmaxf(mx, __shfl_xor(mx, 1));
      mx = fmaxf(mx, __shfl_xor(mx, 2));
      const float mold = mS[r];
      const float mnew = fmaxf(mold, mx);
      float sum = 0.f;
      for (int kk = j; kk < 56; kk += 4) {
        const float p = __expf(Ss[r][kk] - mnew);
        Ss[r][kk] = p;
        sum += p;
      }
      sum += __shfl_xor(sum, 1);
      sum += __shfl_xor(sum, 2);
      if (j == 0) {
        aS[r] = __expf(mold - mnew);
        lS[r] = lS[r] * aS[r] + sum;
        mS[r] = mnew;
      }
    }
    __syncthreads();
#pragma unroll
    for (int p = 0; p < 4; ++p) {
      const int qc = min(p * 16 + qoff, 55);
      f32x4 o = o4[p] * aS[qc];
      for (int kk = 0; kk < 56; ++kk) {
        const float sp = Ss[qc][kk];
        const f32x4 vv = *(const f32x4*)&Vs[kk][d4 * 4];
        o += vv * sp;
      }
      o4[p] = o;
    }
    __syncthreads();
  }

  const int b = bh / H_, h = bh % H_;
#pragma unroll
  for (int p = 0; p < 4; ++p) {
    const int qq = p * 16 + qoff;
    if (qq < 56) {
      const size_t m = (size_t)(b0 + b) * N_ + qt * 56 + qq;
      f32x4 o = o4[p] * (1.f / lS[qq]);
      *(f32x4*)&xout[m * C_ + h * 64 + d4 * 4] = o;
    }
  }
}

// ------------------------------------------------------------------
// Agent attention (flash): per chunk-local (b,h), 49 agents x 1176 keys.
// ------------------------------------------------------------------
__global__ __launch_bounds__(256) void attn_agent(
    const float* __restrict__ agent, const float* __restrict__ k,
    const float* __restrict__ v, float* __restrict__ agent_v) {
  const int bh = blockIdx.x;
  const int tid = threadIdx.x;
  __shared__ float Gs[49][68], Ks[56][68], Vs[56][68], Ss[49][57];
  __shared__ float mS[49], lS[49], aS[49];

  for (int it = tid; it < 49 * 16; it += 256) {
    const int r = it >> 4, c4 = (it & 15) << 2;
    *(float4*)&Gs[r][c4] = *(const float4*)&agent[((size_t)bh * AG_ + r) * HD_ + c4];
  }
  if (tid < 49) { mS[tid] = -1e30f; lS[tid] = 0.f; }
  const int d4 = tid & 15, qoff = tid >> 4;
  f32x4 o4[4];
#pragma unroll
  for (int p = 0; p < 4; ++p) o4[p] = (f32x4)0.f;
  __syncthreads();

  for (int kt = 0; kt < 21; ++kt) {
    const float* kbase = k + ((size_t)bh * N_ + kt * 56) * HD_;
    const float* vbase = v + ((size_t)bh * N_ + kt * 56) * HD_;
    for (int it = tid; it < 56 * 16; it += 256) {
      const int r = it >> 4, c4 = (it & 15) << 2;
      *(float4*)&Ks[r][c4] = *(const float4*)&kbase[r * HD_ + c4];
      *(float4*)&Vs[r][c4] = *(const float4*)&vbase[r * HD_ + c4];
    }
    __syncthreads();
    for (int idx = tid; idx < 49 * 56; idx += 256) {
      const int qq = idx / 56, kk = idx % 56;
      float s = 0.f;
#pragma unroll
      for (int dd = 0; dd < 16; ++dd) {
        const float4 qa = *(const float4*)&Gs[qq][dd * 4];
        const float4 ka = *(const float4*)&Ks[kk][dd * 4];
        s += qa.x * ka.x + qa.y * ka.y + qa.z * ka.z + qa.w * ka.w;
      }
      Ss[qq][kk] = s * SCALE_;
    }
    __syncthreads();
    if (tid < 196) {
      const int r = tid >> 2, j = tid & 3;
      float mx = -1e30f;
      for (int kk = j; kk < 56; kk += 4) mx = fmaxf(mx, Ss[r][kk]);
      mx = fmaxf(mx, __shfl_xor(mx, 1));
      mx = fmaxf(mx, __shfl_xor(mx, 2));
      const float mold = mS[r];
      const float mnew = fmaxf(mold, mx);
      float sum = 0.f;
      for (int kk = j; kk < 56; kk += 4) {
        const float p = __expf(Ss[r][kk] - mnew);
        Ss[r][kk] = p;
        sum += p;
      }
      sum += __shfl_xor(sum, 1);
      sum += __shfl_xor(sum, 2);
      if (j == 0) {
        aS[r] = __expf(mold - mnew);
        lS[r] = lS[r] * aS[r] + sum;
        mS[r] = mnew;
      }
    }
    __syncthreads();
#pragma unroll
    for (int p = 0; p < 4; ++p) {
      const int qc = min(p * 16 + qoff, 48);
      f32x4 o = o4[p] * aS[qc];
      for (int kk = 0; kk < 56; ++kk) {
        const float sp = Ss[qc][kk];
        const f32x4 vv = *(const f32x4*)&Vs[kk][d4 * 4];
        o += vv * sp;
      }
      o4[p] = o;
    }
    __syncthreads();
  }
#pragma unroll
  for (int p = 0; p < 4; ++p) {
    const int qq = p * 16 + qoff;
    if (qq < AG_) {
      f32x4 o = o4[p] * (1.f / lS[qq]);
      *(f32x4*)&agent_v[((size_t)bh * AG_ + qq) * HD_ + d4 * 4] = o;
    }
  }
}

// ------------------------------------------------------------------
// q_s attention over 49 agents + PV with agent_v (single-pass softmax).
// ------------------------------------------------------------------
__global__ __launch_bounds__(256) void attn_qs(const float* __restrict__ q,
                                               const float* __restrict__ agent,
                                               const float* __restrict__ agent_v,
                                               float* __restrict__ xout, int b0) {
  const int bh = blockIdx.x;
  const int qt = blockIdx.y;  // 0..13
  const int tid = threadIdx.x;
  __shared__ float Qs[56][68], Gs[49][68], Vs[49][68], Ss[56][53];

  const float* qbase = q + ((size_t)bh * N_ + NMT_ + qt * 56) * HD_;
  for (int it = tid; it < 56 * 16; it += 256) {
    const int r = it >> 4, c4 = (it & 15) << 2;
    *(float4*)&Qs[r][c4] = *(const float4*)&qbase[r * HD_ + c4];
  }
  for (int it = tid; it < 49 * 16; it += 256) {
    const int r = it >> 4, c4 = (it & 15) << 2;
    *(float4*)&Gs[r][c4] = *(const float4*)&agent[((size_t)bh * AG_ + r) * HD_ + c4];
    *(float4*)&Vs[r][c4] = *(const float4*)&agent_v[((size_t)bh * AG_ + r) * HD_ + c4];
  }
  __syncthreads();
  for (int idx = tid; idx < 56 * AG_; idx += 256) {
    const int qq = idx / AG_, a = idx % AG_;
    float s = 0.f;
#pragma unroll
    for (int dd = 0; dd < 16; ++dd) {
      const float4 qa = *(const float4*)&Qs[qq][dd * 4];
      const float4 ga = *(const float4*)&Gs[a][dd * 4];
      s += qa.x * ga.x + qa.y * ga.y + qa.z * ga.z + qa.w * ga.w;
    }
    Ss[qq][a] = s * SCALE_;
  }
  __syncthreads();
  if (tid < 224) {
    const int r = tid >> 2, j = tid & 3;
    float mx = -1e30f;
    for (int a = j; a < AG_; a += 4) mx = fmaxf(mx, Ss[r][a]);
    mx = fmaxf(mx, __shfl_xor(mx, 1));
    mx = fmaxf(mx, __shfl_xor(mx, 2));
    float sum = 0.f;
    for (int a = j; a < AG_; a += 4) sum += __expf(Ss[r][a] - mx);
    sum += __shfl_xor(sum, 1);
    sum += __shfl_xor(sum, 2);
    const float inv = 1.f / sum;
    for (int a = j; a < AG_; a += 4) Ss[r][a] = __expf(Ss[r][a] - mx) * inv;
  }
  __syncthreads();
  const int d4 = tid & 15, qoff = tid >> 4;
  const int b = bh / H_, h = bh % H_;
#pragma unroll
  for (int p = 0; p < 4; ++p) {
    const int qq = p * 16 + qoff;
    const int qc = min(qq, 55);
    f32x4 o = (f32x4)0.f;
    for (int a = 0; a < AG_; ++a) {
      const float sp = Ss[qc][a];
      const f32x4 vv = *(const f32x4*)&Vs[a][d4 * 4];
      o += vv * sp;
    }
    if (qq < 56) {
      const size_t m = (size_t)(b0 + b) * N_ + NMT_ + qt * 56 + qq;
      *(f32x4*)&xout[m * C_ + h * 64 + d4 * 4] = o;
    }
  }
}

// ------------------------------------------------------------------
extern "C" void kernel_launch(void* const* d_in, const int* in_sizes, int n_in,
                              void* d_out, int out_size, void* d_ws,
                              size_t ws_size, hipStream_t stream) {
  const float* x = (const float*)d_in[0];
  const float* qkv_w = (const float*)d_in[1];
  const float* qkv_b = (const float*)d_in[2];
  const float* proj_w = (const float*)d_in[3];
  const float* proj_b = (const float*)d_in[4];
  float* out = (float*)d_out;
  float* ws = (float*)d_ws;

  const size_t qkv_f = (size_t)H_ * N_ * HD_;            // per-batch q|k|v floats
  const size_t ag_f = (size_t)H_ * AG_ * HD_;            // per-batch agent floats
  const size_t per_batch = 3 * qkv_f + 2 * ag_f;
  const size_t concat_f = (size_t)B_ * N_ * C_;          // 28,901,376

  int cb = 1;
  const int cands[6] = {32, 16, 8, 4, 2, 1};
  for (int i = 0; i < 6; ++i) {
    if ((concat_f + (size_t)cands[i] * per_batch) * 4 <= ws_size) { cb = cands[i]; break; }
  }

  float* concat = ws;
  float* qb = ws + concat_f;
  float* kb = qb + (size_t)cb * qkv_f;
  float* vb = kb + (size_t)cb * qkv_f;
  float* agent = vb + (size_t)cb * qkv_f;
  float* agentv = agent + (size_t)cb * ag_f;

  const int nch = B_ / cb;
  for (int ch = 0; ch < nch; ++ch) {
    const int b0 = ch * cb;
    const int Mch = cb * N_;
    gemm_split<0><<<dim3((Mch + 127) / 128, 18), 256, 0, stream>>>(
        x + (size_t)b0 * N_ * C_, qkv_w, qkv_b, nullptr, qb, kb, vb, Mch);
    agent_pool<<<dim3(cb * 147), 256, 0, stream>>>(qb, agent);
    attn_agent<<<dim3(cb * H_), 256, 0, stream>>>(agent, kb, vb, agentv);
    attn_mt<<<dim3(cb * H_, 7), 256, 0, stream>>>(qb, kb, vb, concat, b0);
    attn_qs<<<dim3(cb * H_, 14), 256, 0, stream>>>(qb, agent, agentv, concat, b0);
  }
  gemm_split<1><<<dim3(294, 6), 256, 0, stream>>>(
      concat, proj_w, proj_b, out, nullptr, nullptr, nullptr, 37632);
}

// Round 6
// 634.939 us; speedup vs baseline: 9.4472x; 3.7060x over previous
//
#include <hip/hip_runtime.h>

typedef __attribute__((ext_vector_type(8))) short short8;
typedef __attribute__((ext_vector_type(4))) short short4v;
typedef __attribute__((ext_vector_type(4))) float f32x4;
typedef unsigned short u16;

#define B_    32
#define N_    1176
#define C_    768
#define H_    12
#define HD_   64
#define NMT_  392
#define AG_   49
#define NEGBIG_ (-1.0e4f)

__device__ __forceinline__ u16 f2bf(float f) {
  unsigned u = __float_as_uint(f);
  unsigned r = (u + 0x7fffu + ((u >> 16) & 1u)) >> 16;
  return (u16)r;
}
__device__ __forceinline__ float bf2f(u16 s) {
  return __uint_as_float(((unsigned)s) << 16);
}

// ------------------------------------------------------------------
// fp32 -> bf16 hi (and optional lo) split, vectorized.
// ------------------------------------------------------------------
template <int LO>
__global__ __launch_bounds__(256) void splitf(const float* __restrict__ in,
                                              u16* __restrict__ hi,
                                              u16* __restrict__ lo, int n4) {
  int i = blockIdx.x * 256 + threadIdx.x;
  const int stride = gridDim.x * 256;
  for (; i < n4; i += stride) {
    const float4 v = ((const float4*)in)[i];
    const float f[4] = {v.x, v.y, v.z, v.w};
    short4v h, l;
#pragma unroll
    for (int e = 0; e < 4; ++e) {
      u16 hb = f2bf(f[e]);
      h[e] = (short)hb;
      if (LO) l[e] = (short)f2bf(f[e] - bf2f(hb));
    }
    ((short4v*)hi)[i] = h;
    if (LO) ((short4v*)lo)[i] = l;
  }
}

// ------------------------------------------------------------------
// QKV GEMM, plain bf16: A(M,768)bf16 @ Bw(2304,768)^T + bias -> q/k bf16
// (b,h,n,d) and v bf16 TRANSPOSED (b,h,d,n). 128x128 tile, BK=32.
// ------------------------------------------------------------------
__global__ __launch_bounds__(256, 2) void gemm_qkv(
    const u16* __restrict__ A, const u16* __restrict__ Bw,
    const float* __restrict__ bias, u16* __restrict__ qb, u16* __restrict__ kb,
    u16* __restrict__ vb, int Mch) {
  __shared__ u16 As[128 * 32], Bs[128 * 32];
  const int tid = threadIdx.x;
  const int m0 = blockIdx.x * 128, c0 = blockIdx.y * 128;
  const int lane = tid & 63, w = tid >> 6;
  const int wr = w >> 1, wc = w & 1;
  const int fr = lane & 15, ko = lane >> 4;

  f32x4 acc[4][4];
#pragma unroll
  for (int m = 0; m < 4; ++m)
#pragma unroll
    for (int n = 0; n < 4; ++n) acc[m][n] = (f32x4)0.f;

  for (int kt = 0; kt < 24; ++kt) {
#pragma unroll
    for (int i = 0; i < 2; ++i) {
      const int ch = tid + i * 256;
      const int row = ch >> 2, c8 = (ch & 3) << 3;
      const int ar = min(m0 + row, Mch - 1);
      const short8 av = *(const short8*)&A[(size_t)ar * 768 + kt * 32 + c8];
      const short8 bv = *(const short8*)&Bw[(size_t)(c0 + row) * 768 + kt * 32 + c8];
      *(short8*)&As[row * 32 + c8] = av;
      *(short8*)&Bs[row * 32 + c8] = bv;
    }
    __syncthreads();
    short8 af[4], bfr[4];
#pragma unroll
    for (int m = 0; m < 4; ++m) af[m] = *(const short8*)&As[(wr * 64 + m * 16 + fr) * 32 + ko * 8];
#pragma unroll
    for (int n = 0; n < 4; ++n) bfr[n] = *(const short8*)&Bs[(wc * 64 + n * 16 + fr) * 32 + ko * 8];
#pragma unroll
    for (int m = 0; m < 4; ++m)
#pragma unroll
      for (int n = 0; n < 4; ++n)
        acc[m][n] = __builtin_amdgcn_mfma_f32_16x16x32_bf16(af[m], bfr[n], acc[m][n], 0, 0, 0);
    __syncthreads();
  }

  const int colbase = c0 + wc * 64;  // 64-aligned -> (t,h) uniform per wave
  const int t = colbase / 768;
  const int h = (colbase % 768) >> 6;
#pragma unroll
  for (int n = 0; n < 4; ++n) {
    const int d = n * 16 + fr;
    const float bv = bias[colbase + d];
#pragma unroll
    for (int m = 0; m < 4; ++m) {
      const int mg = m0 + wr * 64 + m * 16 + ko * 4;
      if (mg < Mch) {
        const int bl = mg / N_, nt = mg - bl * N_;
        if (t == 2) {
          short4v vv;
#pragma unroll
          for (int r = 0; r < 4; ++r) vv[r] = (short)f2bf(acc[m][n][r] + bv);
          *(short4v*)&vb[(((size_t)bl * H_ + h) * HD_ + d) * N_ + nt] = vv;
        } else {
          u16* dst = (t == 0) ? qb : kb;
#pragma unroll
          for (int r = 0; r < 4; ++r)
            dst[(((size_t)bl * H_ + h) * N_ + nt + r) * HD_ + d] = f2bf(acc[m][n][r] + bv);
        }
      }
    }
  }
}

// ------------------------------------------------------------------
// Proj GEMM, 3-term split bf16: out = (Ah+Al)@(Bh+Bl)^T + bias (drop AlBl).
// FIX (R6): staging loop now covers all 128 tile rows (was 64 -> rows
// 64..127 were uninitialized LDS -> NaN in wr/wc=1 wave quadrants).
// ------------------------------------------------------------------
__global__ __launch_bounds__(256, 2) void gemm_proj(
    const u16* __restrict__ Ahg, const u16* __restrict__ Alg,
    const u16* __restrict__ Bhg, const u16* __restrict__ Blg,
    const float* __restrict__ bias, float* __restrict__ out) {
  __shared__ u16 Ah[128 * 32], Al[128 * 32], Bh[128 * 32], Bl[128 * 32];
  const int tid = threadIdx.x;
  const int m0 = blockIdx.x * 128, c0 = blockIdx.y * 128;
  const int lane = tid & 63, w = tid >> 6;
  const int wr = w >> 1, wc = w & 1;
  const int fr = lane & 15, ko = lane >> 4;

  f32x4 acc[4][4];
#pragma unroll
  for (int m = 0; m < 4; ++m)
#pragma unroll
    for (int n = 0; n < 4; ++n) acc[m][n] = (f32x4)0.f;

  for (int kt = 0; kt < 24; ++kt) {
#pragma unroll
    for (int i = 0; i < 2; ++i) {
      const int ch = tid + i * 256;
      const int row = ch >> 2, c8 = (ch & 3) << 3;
      const size_t aoff = (size_t)(m0 + row) * 768 + kt * 32 + c8;
      const size_t boff = (size_t)(c0 + row) * 768 + kt * 32 + c8;
      *(short8*)&Ah[row * 32 + c8] = *(const short8*)&Ahg[aoff];
      *(short8*)&Al[row * 32 + c8] = *(const short8*)&Alg[aoff];
      *(short8*)&Bh[row * 32 + c8] = *(const short8*)&Bhg[boff];
      *(short8*)&Bl[row * 32 + c8] = *(const short8*)&Blg[boff];
    }
    __syncthreads();
    short8 ah[4], al[4], bh[4], bl[4];
#pragma unroll
    for (int m = 0; m < 4; ++m) {
      const int off = (wr * 64 + m * 16 + fr) * 32 + ko * 8;
      ah[m] = *(const short8*)&Ah[off];
      al[m] = *(const short8*)&Al[off];
    }
#pragma unroll
    for (int n = 0; n < 4; ++n) {
      const int off = (wc * 64 + n * 16 + fr) * 32 + ko * 8;
      bh[n] = *(const short8*)&Bh[off];
      bl[n] = *(const short8*)&Bl[off];
    }
#pragma unroll
    for (int m = 0; m < 4; ++m)
#pragma unroll
      for (int n = 0; n < 4; ++n) {
        acc[m][n] = __builtin_amdgcn_mfma_f32_16x16x32_bf16(ah[m], bh[n], acc[m][n], 0, 0, 0);
        acc[m][n] = __builtin_amdgcn_mfma_f32_16x16x32_bf16(ah[m], bl[n], acc[m][n], 0, 0, 0);
        acc[m][n] = __builtin_amdgcn_mfma_f32_16x16x32_bf16(al[m], bh[n], acc[m][n], 0, 0, 0);
      }
    __syncthreads();
  }
#pragma unroll
  for (int n = 0; n < 4; ++n) {
    const int col = c0 + wc * 64 + n * 16 + fr;
    const float bv = bias[col];
#pragma unroll
    for (int m = 0; m < 4; ++m) {
      const int mg = m0 + wr * 64 + m * 16 + ko * 4;
#pragma unroll
      for (int r = 0; r < 4; ++r) out[(size_t)(mg + r) * 768 + col] = acc[m][n][r] + bv;
    }
  }
}

// ------------------------------------------------------------------
// Agent pooling (scrambled reshape), bf16 in/out. Covers a in [0,64):
// rows 49..63 are ZEROED so no consumer ever reads unwritten memory.
// ------------------------------------------------------------------
__global__ __launch_bounds__(256) void agent_pool(const u16* __restrict__ q,
                                                  u16* __restrict__ agent) {
  const int wid = threadIdx.x >> 6;
  const int lane = threadIdx.x & 63;
  const int row = blockIdx.x * 4 + wid;  // (b*12+h2)*64 + a, a in [0,64)
  const int rem = row % (H_ * 64);
  const int b = row / (H_ * 64);
  const int h2 = rem / 64;
  const int a = rem % 64;
  if (a >= AG_) {
    agent[((size_t)b * H_ + h2) * 4096 + a * 64 + lane] = 0;
    return;
  }
  const int ap = a / 7, aq = a % 7;
  float s = 0.f;
#pragma unroll
  for (int i = 0; i < 4; ++i)
#pragma unroll
    for (int j = 0; j < 4; ++j) {
      const int g = (ap * 4 + i) * 336 + (aq * 4 + j) * 12 + h2;
      const int h = g / 784, n = g % 784;
      s += bf2f(q[(((size_t)b * H_ + h) * N_ + NMT_ + n) * HD_ + lane]);
    }
  agent[((size_t)b * H_ + h2) * 4096 + a * 64 + lane] = f2bf(s * 0.0625f);
}

// ------------------------------------------------------------------
// Unified MFMA flash attention (NaN-hardened; see R4/R5 notes).
// ------------------------------------------------------------------
__global__ __launch_bounds__(256, 3) void flash_attn(
    const u16* __restrict__ Q, int q_bh_str, int q_base, int q_row_max, int q_valid,
    const u16* __restrict__ K, int k_bh_str, int k_row_max,
    const u16* __restrict__ Vt, int vt_bh_str, int vt_pitch, int vt_col_max,
    int n_keys, int nkt,
    u16* __restrict__ cch, u16* __restrict__ ccl, int b0,
    u16* __restrict__ avT, int mode) {
  __shared__ u16 Qs[4096], Ks[4096], Vts[4096], Ps[4096];
  __shared__ float Ss[64][65];
  __shared__ float mS[64], lS[64], aS[64];

  const int tid = threadIdx.x, bh = blockIdx.x;
  const int q0 = q_base + blockIdx.y * 56;
  const int lane = tid & 63, w = tid >> 6;
  const int fr = lane & 15, ko = lane >> 4;

  const u16* Qb = Q + (size_t)bh * q_bh_str;
  const u16* Kb = K + (size_t)bh * k_bh_str;
  const u16* Vb = Vt + (size_t)bh * vt_bh_str;

#pragma unroll
  for (int i = 0; i < 2; ++i) {
    const int ch = tid + i * 256;
    const int row = ch >> 3, c8 = (ch & 7) << 3;
    const int qr = min(q0 + row, q_row_max);
    const short8 v = *(const short8*)&Qb[(size_t)qr * 64 + c8];
    *(short8*)&Qs[(row * 64 + c8) ^ ((row & 7) << 3)] = v;
  }
  if (tid < 64) { mS[tid] = NEGBIG_; lS[tid] = 0.f; aS[tid] = 0.f; }

  f32x4 oacc[4];
#pragma unroll
  for (int d = 0; d < 4; ++d) oacc[d] = (f32x4)0.f;

  for (int kt = 0; kt < nkt; ++kt) {
#pragma unroll
    for (int i = 0; i < 2; ++i) {
      const int ch = tid + i * 256;
      const int row = ch >> 3, c8 = (ch & 7) << 3;
      const int kr = min(kt * 64 + row, k_row_max);
      const short8 v = *(const short8*)&Kb[(size_t)kr * 64 + c8];
      *(short8*)&Ks[(row * 64 + c8) ^ ((row & 7) << 3)] = v;
    }
#pragma unroll
    for (int i = 0; i < 2; ++i) {
      const int ch = tid + i * 256;
      const int row = ch >> 3, c8 = (ch & 7) << 3;
      const int col8 = kt * 64 + c8;
      const u16* src = &Vb[(size_t)row * vt_pitch];
      short8 v;
      if (col8 + 8 <= vt_col_max) {
        v = *(const short8*)&src[col8];
      } else {
#pragma unroll
        for (int e = 0; e < 8; ++e) v[e] = (short)src[min(col8 + e, vt_col_max - 1)];
      }
      *(short8*)&Vts[(row * 64 + c8) ^ ((row & 7) << 3)] = v;
    }
    __syncthreads();

    // ---- S = Q K^T * 0.125 (MFMA), masked -> finite sentinel
    short8 aq[2];
#pragma unroll
    for (int s = 0; s < 2; ++s)
      aq[s] = *(const short8*)&Qs[((w * 16 + fr) * 64 + s * 32 + ko * 8) ^ ((fr & 7) << 3)];
#pragma unroll
    for (int j = 0; j < 4; ++j) {
      f32x4 sa = (f32x4)0.f;
#pragma unroll
      for (int s = 0; s < 2; ++s) {
        const short8 bk = *(const short8*)&Ks[((j * 16 + fr) * 64 + s * 32 + ko * 8) ^ ((fr & 7) << 3)];
        sa = __builtin_amdgcn_mfma_f32_16x16x32_bf16(aq[s], bk, sa, 0, 0, 0);
      }
      const int colg = kt * 64 + j * 16 + fr;
      const bool maskc = (colg >= n_keys);
#pragma unroll
      for (int r = 0; r < 4; ++r) {
        const int srow = w * 16 + ko * 4 + r;
        Ss[srow][j * 16 + fr] = maskc ? NEGBIG_ : sa[r] * 0.125f;
      }
    }
    __syncthreads();

    // ---- online softmax; masked P explicitly zero
    {
      const int r = tid >> 2, jj = tid & 3;
      float sv[16];
      float mx = NEGBIG_;
#pragma unroll
      for (int c = 0; c < 16; ++c) {
        sv[c] = Ss[r][jj * 16 + c];
        mx = fmaxf(mx, sv[c]);
      }
      mx = fmaxf(mx, __shfl_xor(mx, 1));
      mx = fmaxf(mx, __shfl_xor(mx, 2));
      const float mold = mS[r];
      const float mnew = fmaxf(mold, mx);
      float sum = 0.f;
#pragma unroll
      for (int c = 0; c < 16; ++c) {
        const bool mk = (kt * 64 + jj * 16 + c) >= n_keys;
        const float p = mk ? 0.f : __expf(sv[c] - mnew);
        sum += p;
        Ps[(r * 64 + jj * 16 + c) ^ ((r & 7) << 3)] = f2bf(p);
      }
      sum += __shfl_xor(sum, 1);
      sum += __shfl_xor(sum, 2);
      if (jj == 0) {
        const float alpha = __expf(mold - mnew);
        aS[r] = alpha;
        lS[r] = lS[r] * alpha + sum;
        mS[r] = mnew;
      }
    }
    __syncthreads();

    // ---- O = O*alpha + P V (MFMA)
    float al[4];
#pragma unroll
    for (int r = 0; r < 4; ++r) al[r] = aS[w * 16 + ko * 4 + r];
    short8 ap[2];
#pragma unroll
    for (int s = 0; s < 2; ++s)
      ap[s] = *(const short8*)&Ps[((w * 16 + fr) * 64 + s * 32 + ko * 8) ^ ((fr & 7) << 3)];
#pragma unroll
    for (int dj = 0; dj < 4; ++dj) {
      f32x4 o = oacc[dj];
#pragma unroll
      for (int r = 0; r < 4; ++r) o[r] *= al[r];
#pragma unroll
      for (int s = 0; s < 2; ++s) {
        const short8 bv = *(const short8*)&Vts[((dj * 16 + fr) * 64 + s * 32 + ko * 8) ^ ((fr & 7) << 3)];
        o = __builtin_amdgcn_mfma_f32_16x16x32_bf16(ap[s], bv, o, 0, 0, 0);
      }
      oacc[dj] = o;
    }
    __syncthreads();
  }

  float linv[4];
#pragma unroll
  for (int r = 0; r < 4; ++r) linv[r] = 1.f / fmaxf(lS[w * 16 + ko * 4 + r], 1e-30f);

  if (mode == 0) {
    const int b = bh / H_, h = bh % H_;
#pragma unroll
    for (int dj = 0; dj < 4; ++dj)
#pragma unroll
      for (int r = 0; r < 4; ++r) {
        const int rowl = w * 16 + ko * 4 + r;
        if (rowl < q_valid) {
          const size_t m = (size_t)(b0 + b) * N_ + q0 + rowl;
          const float val = oacc[dj][r] * linv[r];
          const u16 hb = f2bf(val);
          const u16 lb = f2bf(val - bf2f(hb));
          const size_t idx = m * 768 + h * 64 + dj * 16 + fr;
          cch[idx] = hb;
          ccl[idx] = lb;
        }
      }
  } else {
    // write ALL 64 rows so avT has no unwritten bytes
#pragma unroll
    for (int dj = 0; dj < 4; ++dj)
#pragma unroll
      for (int r = 0; r < 4; ++r) {
        const int a = w * 16 + ko * 4 + r;
        avT[(size_t)bh * 4096 + (dj * 16 + fr) * 64 + a] = f2bf(oacc[dj][r] * linv[r]);
      }
  }
}

// ------------------------------------------------------------------
extern "C" void kernel_launch(void* const* d_in, const int* in_sizes, int n_in,
                              void* d_out, int out_size, void* d_ws,
                              size_t ws_size, hipStream_t stream) {
  const float* x = (const float*)d_in[0];
  const float* qkv_w = (const float*)d_in[1];
  const float* qkv_b = (const float*)d_in[2];
  const float* proj_w = (const float*)d_in[3];
  const float* proj_b = (const float*)d_in[4];
  float* out = (float*)d_out;
  u16* ws = (u16*)d_ws;

  const size_t XBF = 28901376ull;       // 37632*768
  const size_t QW = 2304ull * 768;
  const size_t PW = 768ull * 768;
  const size_t QKV1 = (size_t)H_ * N_ * HD_;  // per-batch per-tensor
  const size_t AG1 = (size_t)H_ * 64 * 64;    // per-batch (padded)

  size_t o = 0;
  u16* xbf = ws + o; o += XBF;
  u16* qwh = ws + o; o += QW;
  u16* pwh = ws + o; o += PW;
  u16* pwl = ws + o; o += PW;
  u16* cch = ws + o; o += XBF;
  u16* ccl = ws + o; o += XBF;
  const size_t fixed_sh = o;
  const size_t per_sh = 3 * QKV1 + 2 * AG1;

  int cb = 1;
  const int cands[6] = {32, 16, 8, 4, 2, 1};
  for (int i = 0; i < 6; ++i)
    if ((fixed_sh + (size_t)cands[i] * per_sh) * 2 <= ws_size) { cb = cands[i]; break; }

  u16* qb = ws + o; o += cb * QKV1;
  u16* kb = ws + o; o += cb * QKV1;
  u16* vb = ws + o; o += cb * QKV1;
  u16* agent = ws + o; o += cb * AG1;
  u16* avT = ws + o; o += cb * AG1;

  splitf<0><<<2048, 256, 0, stream>>>(x, xbf, nullptr, (int)(XBF / 4));
  splitf<0><<<1024, 256, 0, stream>>>(qkv_w, qwh, nullptr, (int)(QW / 4));
  splitf<1><<<512, 256, 0, stream>>>(proj_w, pwh, pwl, (int)(PW / 4));

  const int nch = B_ / cb;
  for (int chn = 0; chn < nch; ++chn) {
    const int b0 = chn * cb;
    const int Mch = cb * N_;
    gemm_qkv<<<dim3((Mch + 127) / 128, 18), 256, 0, stream>>>(
        xbf + (size_t)b0 * N_ * 768, qwh, qkv_b, qb, kb, vb, Mch);
    agent_pool<<<dim3(cb * 192), 256, 0, stream>>>(qb, agent);
    // agent attention: 49 agents vs all 1176 keys -> avT (d-major)
    flash_attn<<<dim3(cb * H_, 1), 256, 0, stream>>>(
        agent, 4096, 0, 48, AG_, kb, N_ * HD_, N_ - 1,
        vb, N_ * HD_, N_, N_, N_, 19, nullptr, nullptr, b0, avT, 1);
    // MT attention: 392 x 392
    flash_attn<<<dim3(cb * H_, 7), 256, 0, stream>>>(
        qb, N_ * HD_, 0, N_ - 1, 56, kb, N_ * HD_, N_ - 1,
        vb, N_ * HD_, N_, N_, NMT_, 7, cch, ccl, b0, nullptr, 0);
    // q_s attention: 784 x 49 agents
    flash_attn<<<dim3(cb * H_, 14), 256, 0, stream>>>(
        qb, N_ * HD_, NMT_, N_ - 1, 56, agent, 4096, 63,
        avT, 4096, 64, 64, AG_, 1, cch, ccl, b0, nullptr, 0);
  }
  gemm_proj<<<dim3(294, 6), 256, 0, stream>>>(cch, ccl, pwh, pwl, proj_b, out);
}